// Round 1
// baseline (533.060 us; speedup 1.0000x reference)
//
#include <hip/hip_runtime.h>

#define C 128

// ---------------- degree histogram ----------------
__global__ void count_deg_kernel(const int* __restrict__ dst, int* __restrict__ deg, int E) {
    int e = blockIdx.x * blockDim.x + threadIdx.x;
    if (e < E) atomicAdd(&deg[dst[e]], 1);
}

// ---------------- exclusive scan (single block) ----------------
__global__ void scan_kernel(const int* __restrict__ deg, int* __restrict__ row_start,
                            int* __restrict__ cursor, float* __restrict__ inv_deg, int n) {
    __shared__ int part[256];
    int tid = threadIdx.x;
    int chunk = (n + 255) / 256;
    int begin = tid * chunk;
    int end = min(begin + chunk, n);
    int s = 0;
    for (int i = begin; i < end; ++i) s += deg[i];
    part[tid] = s;
    __syncthreads();
    // Hillis-Steele inclusive scan
    for (int off = 1; off < 256; off <<= 1) {
        int v = (tid >= off) ? part[tid - off] : 0;
        __syncthreads();
        part[tid] += v;
        __syncthreads();
    }
    int run = (tid == 0) ? 0 : part[tid - 1];
    for (int i = begin; i < end; ++i) {
        int d = deg[i];
        row_start[i] = run;
        cursor[i] = run;
        inv_deg[i] = 1.0f / fmaxf((float)d, 1.0f);
        run += d;
    }
    if (tid == 255) row_start[n] = run;
}

// ---------------- bucket edges by dst (counting sort) ----------------
__global__ void bucket_kernel(const int* __restrict__ src, const int* __restrict__ dst,
                              int* __restrict__ cursor, int* __restrict__ esrc, int E) {
    int e = blockIdx.x * blockDim.x + threadIdx.x;
    if (e < E) {
        int d = dst[e];
        int p = atomicAdd(&cursor[d], 1);
        esrc[p] = src[e];
    }
}

// ---------------- mean aggregation: one wave per node ----------------
__global__ void aggregate_kernel(const float* __restrict__ x, const int* __restrict__ row_start,
                                 const int* __restrict__ esrc, const float* __restrict__ inv_deg,
                                 float* __restrict__ agg, int n) {
    int wave = (blockIdx.x * blockDim.x + threadIdx.x) >> 6;
    int lane = threadIdx.x & 63;
    if (wave >= n) return;
    int beg = row_start[wave];
    int end = row_start[wave + 1];
    float ax = 0.f, ay = 0.f;
    int i = beg;
    for (; i + 1 < end; i += 2) {
        int s0 = esrc[i], s1 = esrc[i + 1];
        float2 v0 = *(const float2*)(x + (size_t)s0 * C + lane * 2);
        float2 v1 = *(const float2*)(x + (size_t)s1 * C + lane * 2);
        ax += v0.x + v1.x;
        ay += v0.y + v1.y;
    }
    if (i < end) {
        int s0 = esrc[i];
        float2 v0 = *(const float2*)(x + (size_t)s0 * C + lane * 2);
        ax += v0.x;
        ay += v0.y;
    }
    float sc = inv_deg[wave];
    float2 r;
    r.x = ax * sc;
    r.y = ay * sc;
    *(float2*)(agg + (size_t)wave * C + lane * 2) = r;
}

// ---------------- fused GEMM (h = agg@Wn^T + x@Wr^T + b) + LayerNorm + ReLU ----------------
// 64-row tile, full 128-col width. 256 threads: ty=tid>>4 covers 4 rows, tx=tid&15
// covers cols tx+16*j (interleaved -> conflict-free LDS b-reads).
__launch_bounds__(256, 2)
__global__ void gemm_ln_relu_kernel(const float* __restrict__ Aagg, const float* __restrict__ Xin,
                                    const float* __restrict__ Wn, const float* __restrict__ Wr,
                                    const float* __restrict__ bconv, const float* __restrict__ gamma,
                                    const float* __restrict__ beta, float* __restrict__ Xout, int n) {
    __shared__ float As[64][17];    // [row][k-chunk], pad 17 -> broadcast-friendly a-reads
    __shared__ float Ws[16][132];   // [k][col], pad 132 keeps 16B-aligned rows
    int tid = threadIdx.x;
    int ty = tid >> 4;
    int tx = tid & 15;
    int row0 = blockIdx.x * 64;
    float acc[4][8];
#pragma unroll
    for (int i = 0; i < 4; ++i)
#pragma unroll
        for (int j = 0; j < 8; ++j) acc[i][j] = 0.f;

    int arow = tid >> 2, aq = tid & 3;  // A staging: float4 per thread
    int wn = tid >> 1, wq = tid & 1;    // W staging: 2x float4 per thread

    for (int phase = 0; phase < 2; ++phase) {
        const float* Ap = phase ? Xin : Aagg;
        const float* Wp = phase ? Wr : Wn;
        for (int kc = 0; kc < C; kc += 16) {
            __syncthreads();
            {
                float4 v = make_float4(0.f, 0.f, 0.f, 0.f);
                int r = row0 + arow;
                if (r < n) v = *(const float4*)(Ap + (size_t)r * C + kc + aq * 4);
                As[arow][aq * 4 + 0] = v.x;
                As[arow][aq * 4 + 1] = v.y;
                As[arow][aq * 4 + 2] = v.z;
                As[arow][aq * 4 + 3] = v.w;
            }
            {
                float4 v0 = *(const float4*)(Wp + (size_t)wn * C + kc + wq * 8);
                float4 v1 = *(const float4*)(Wp + (size_t)wn * C + kc + wq * 8 + 4);
                Ws[wq * 8 + 0][wn] = v0.x;
                Ws[wq * 8 + 1][wn] = v0.y;
                Ws[wq * 8 + 2][wn] = v0.z;
                Ws[wq * 8 + 3][wn] = v0.w;
                Ws[wq * 8 + 4][wn] = v1.x;
                Ws[wq * 8 + 5][wn] = v1.y;
                Ws[wq * 8 + 6][wn] = v1.z;
                Ws[wq * 8 + 7][wn] = v1.w;
            }
            __syncthreads();
#pragma unroll
            for (int k = 0; k < 16; ++k) {
                float a[4], b[8];
#pragma unroll
                for (int i = 0; i < 4; ++i) a[i] = As[ty * 4 + i][k];
#pragma unroll
                for (int j = 0; j < 8; ++j) b[j] = Ws[k][tx + 16 * j];
#pragma unroll
                for (int i = 0; i < 4; ++i)
#pragma unroll
                    for (int j = 0; j < 8; ++j) acc[i][j] += a[i] * b[j];
            }
        }
    }

    // epilogue: +bias, LayerNorm over the 128 cols (held by 16 tx lanes), ReLU
    float g[8], be[8], bc[8];
#pragma unroll
    for (int j = 0; j < 8; ++j) {
        int c = tx + 16 * j;
        bc[j] = bconv[c];
        g[j] = gamma[c];
        be[j] = beta[c];
    }
#pragma unroll
    for (int i = 0; i < 4; ++i) {
        int r = row0 + ty * 4 + i;
        float s = 0.f, ss = 0.f;
#pragma unroll
        for (int j = 0; j < 8; ++j) {
            float h = acc[i][j] + bc[j];
            acc[i][j] = h;
            s += h;
            ss += h * h;
        }
#pragma unroll
        for (int m = 1; m < 16; m <<= 1) {
            s += __shfl_xor(s, m, 64);
            ss += __shfl_xor(ss, m, 64);
        }
        float mu = s * (1.0f / 128.0f);
        float var = ss * (1.0f / 128.0f) - mu * mu;
        float rs = rsqrtf(var + 1e-5f);
        if (r < n) {
#pragma unroll
            for (int j = 0; j < 8; ++j) {
                float o = (acc[i][j] - mu) * rs * g[j] + be[j];
                Xout[(size_t)r * C + tx + 16 * j] = fmaxf(o, 0.f);
            }
        }
    }
}

// ---------------- head: out = x[:ns] @ Wh^T + bh ----------------
__global__ void head_kernel(const float* __restrict__ x, const float* __restrict__ Wh,
                            const float* __restrict__ bh, float* __restrict__ out) {
    __shared__ float xs[C];
    int s = blockIdx.x;
    int o = threadIdx.x;  // 64 threads
    xs[o] = x[(size_t)s * C + o];
    xs[o + 64] = x[(size_t)s * C + o + 64];
    __syncthreads();
    float acc = bh[o];
    const float4* wr = (const float4*)(Wh + (size_t)o * C);
#pragma unroll
    for (int c4 = 0; c4 < 32; ++c4) {
        float4 w = wr[c4];
        acc += w.x * xs[c4 * 4] + w.y * xs[c4 * 4 + 1] + w.z * xs[c4 * 4 + 2] + w.w * xs[c4 * 4 + 3];
    }
    out[(size_t)s * 64 + o] = acc;
}

extern "C" void kernel_launch(void* const* d_in, const int* in_sizes, int n_in,
                              void* d_out, int out_size, void* d_ws, size_t ws_size,
                              hipStream_t stream) {
    const float* x = (const float*)d_in[0];
    const int* ei = (const int*)d_in[1];
    const float* Wn = (const float*)d_in[2];
    const float* Wr = (const float*)d_in[3];
    const float* bconv = (const float*)d_in[4];
    const float* gamma = (const float*)d_in[5];
    const float* beta = (const float*)d_in[6];
    const float* Wh = (const float*)d_in[7];
    const float* bh = (const float*)d_in[8];

    int N = in_sizes[0] / C;
    int E = in_sizes[1] / 2;
    int L = in_sizes[2] / (C * C);
    int num_seed = out_size / 64;

    char* ws = (char*)d_ws;
    size_t off = 0;
    auto alloc = [&](size_t bytes) {
        void* p = ws + off;
        off = (off + bytes + 255) & ~(size_t)255;
        return p;
    };
    int* deg = (int*)alloc((size_t)N * 4);
    int* row_start = (int*)alloc((size_t)(N + 1) * 4);
    int* cursor = (int*)alloc((size_t)N * 4);
    float* inv_deg = (float*)alloc((size_t)N * 4);
    int* esrc = (int*)alloc((size_t)E * 4);
    float* agg = (float*)alloc((size_t)N * C * 4);
    float* xA = (float*)alloc((size_t)N * C * 4);
    float* xB = (float*)alloc((size_t)N * C * 4);

    const int* srcIdx = ei;
    const int* dstIdx = ei + E;

    hipMemsetAsync(deg, 0, (size_t)N * 4, stream);
    count_deg_kernel<<<(E + 255) / 256, 256, 0, stream>>>(dstIdx, deg, E);
    scan_kernel<<<1, 256, 0, stream>>>(deg, row_start, cursor, inv_deg, N);
    bucket_kernel<<<(E + 255) / 256, 256, 0, stream>>>(srcIdx, dstIdx, cursor, esrc, E);

    const float* cur = x;
    float* bufs[2] = {xA, xB};
    for (int l = 0; l < L; ++l) {
        aggregate_kernel<<<(N * 64 + 255) / 256, 256, 0, stream>>>(cur, row_start, esrc, inv_deg, agg, N);
        float* nxt = bufs[l & 1];
        gemm_ln_relu_kernel<<<(N + 63) / 64, 256, 0, stream>>>(
            agg, cur, Wn + (size_t)l * C * C, Wr + (size_t)l * C * C,
            bconv + (size_t)l * C, gamma + (size_t)l * C, beta + (size_t)l * C, nxt, N);
        cur = nxt;
    }
    head_kernel<<<num_seed, 64, 0, stream>>>(cur, Wh, bh, (float*)d_out);
}

// Round 2
// 396.356 us; speedup vs baseline: 1.3449x; 1.3449x over previous
//
#include <hip/hip_runtime.h>

#define C 128

// ---------------- degree histogram ----------------
__global__ void count_deg_kernel(const int* __restrict__ dst, int* __restrict__ deg, int E) {
    int e = blockIdx.x * blockDim.x + threadIdx.x;
    if (e < E) atomicAdd(&deg[dst[e]], 1);
}

// ---------------- parallel exclusive scan over deg[] (3 phases) ----------------
// Phase 1: per-256-chunk sums
__global__ void scan_partial_kernel(const int* __restrict__ deg, int* __restrict__ blocksum, int n) {
    __shared__ int sm[256];
    int t = threadIdx.x;
    int i = blockIdx.x * 256 + t;
    sm[t] = (i < n) ? deg[i] : 0;
    __syncthreads();
#pragma unroll
    for (int off = 128; off > 0; off >>= 1) {
        if (t < off) sm[t] += sm[t + off];
        __syncthreads();
    }
    if (t == 0) blocksum[blockIdx.x] = sm[0];
}

// Phase 2: single tiny block scans the block sums -> exclusive block offsets
__global__ void scan_block_kernel(const int* __restrict__ blocksum, int* __restrict__ blockoff, int nb) {
    __shared__ int sm[256];
    int t = threadIdx.x;
    // serial-chunk fallback keeps correctness for nb > 256 (not hit at N=50000)
    int chunk = (nb + 255) / 256;
    int begin = t * chunk, end = min(begin + chunk, nb);
    int s = 0;
    for (int i = begin; i < end; ++i) s += blocksum[i];
    sm[t] = s;
    __syncthreads();
    for (int off = 1; off < 256; off <<= 1) {
        int v = (t >= off) ? sm[t - off] : 0;
        __syncthreads();
        sm[t] += v;
        __syncthreads();
    }
    int run = (t == 0) ? 0 : sm[t - 1];
    for (int i = begin; i < end; ++i) {
        blockoff[i] = run;
        run += blocksum[i];
    }
}

// Phase 3: per-chunk inclusive scan + block offset -> row_start/cursor/inv_deg
__global__ void scan_scatter_kernel(const int* __restrict__ deg, const int* __restrict__ blockoff,
                                    int* __restrict__ row_start, int* __restrict__ cursor,
                                    float* __restrict__ inv_deg, int n, int E) {
    __shared__ int sm[256];
    int t = threadIdx.x;
    int i = blockIdx.x * 256 + t;
    int d = (i < n) ? deg[i] : 0;
    sm[t] = d;
    __syncthreads();
    for (int off = 1; off < 256; off <<= 1) {
        int v = (t >= off) ? sm[t - off] : 0;
        __syncthreads();
        sm[t] += v;
        __syncthreads();
    }
    int excl = sm[t] - d + blockoff[blockIdx.x];
    if (i < n) {
        row_start[i] = excl;
        cursor[i] = excl;
        inv_deg[i] = 1.0f / fmaxf((float)d, 1.0f);
    }
    if (i == n - 1) row_start[n] = E;
}

// ---------------- bucket edges by dst (counting sort) ----------------
__global__ void bucket_kernel(const int* __restrict__ src, const int* __restrict__ dst,
                              int* __restrict__ cursor, int* __restrict__ esrc, int E) {
    int e = blockIdx.x * blockDim.x + threadIdx.x;
    if (e < E) {
        int d = dst[e];
        int p = atomicAdd(&cursor[d], 1);
        esrc[p] = src[e];
    }
}

// ---------------- mean aggregation: one wave per node ----------------
__global__ void aggregate_kernel(const float* __restrict__ x, const int* __restrict__ row_start,
                                 const int* __restrict__ esrc, const float* __restrict__ inv_deg,
                                 float* __restrict__ agg, int n) {
    int wave = (blockIdx.x * blockDim.x + threadIdx.x) >> 6;
    int lane = threadIdx.x & 63;
    if (wave >= n) return;
    int beg = row_start[wave];
    int end = row_start[wave + 1];
    float ax = 0.f, ay = 0.f;
    int i = beg;
    for (; i + 1 < end; i += 2) {
        int s0 = esrc[i], s1 = esrc[i + 1];
        float2 v0 = *(const float2*)(x + (size_t)s0 * C + lane * 2);
        float2 v1 = *(const float2*)(x + (size_t)s1 * C + lane * 2);
        ax += v0.x + v1.x;
        ay += v0.y + v1.y;
    }
    if (i < end) {
        int s0 = esrc[i];
        float2 v0 = *(const float2*)(x + (size_t)s0 * C + lane * 2);
        ax += v0.x;
        ay += v0.y;
    }
    float sc = inv_deg[wave];
    float2 r;
    r.x = ax * sc;
    r.y = ay * sc;
    *(float2*)(agg + (size_t)wave * C + lane * 2) = r;
}

// ---------------- fused GEMM (h = agg@Wn^T + x@Wr^T + b) + LayerNorm + ReLU ----------------
__launch_bounds__(256, 2)
__global__ void gemm_ln_relu_kernel(const float* __restrict__ Aagg, const float* __restrict__ Xin,
                                    const float* __restrict__ Wn, const float* __restrict__ Wr,
                                    const float* __restrict__ bconv, const float* __restrict__ gamma,
                                    const float* __restrict__ beta, float* __restrict__ Xout, int n) {
    __shared__ float As[64][17];
    __shared__ float Ws[16][132];
    int tid = threadIdx.x;
    int ty = tid >> 4;
    int tx = tid & 15;
    int row0 = blockIdx.x * 64;
    float acc[4][8];
#pragma unroll
    for (int i = 0; i < 4; ++i)
#pragma unroll
        for (int j = 0; j < 8; ++j) acc[i][j] = 0.f;

    int arow = tid >> 2, aq = tid & 3;
    int wn = tid >> 1, wq = tid & 1;

    for (int phase = 0; phase < 2; ++phase) {
        const float* Ap = phase ? Xin : Aagg;
        const float* Wp = phase ? Wr : Wn;
        for (int kc = 0; kc < C; kc += 16) {
            __syncthreads();
            {
                float4 v = make_float4(0.f, 0.f, 0.f, 0.f);
                int r = row0 + arow;
                if (r < n) v = *(const float4*)(Ap + (size_t)r * C + kc + aq * 4);
                As[arow][aq * 4 + 0] = v.x;
                As[arow][aq * 4 + 1] = v.y;
                As[arow][aq * 4 + 2] = v.z;
                As[arow][aq * 4 + 3] = v.w;
            }
            {
                float4 v0 = *(const float4*)(Wp + (size_t)wn * C + kc + wq * 8);
                float4 v1 = *(const float4*)(Wp + (size_t)wn * C + kc + wq * 8 + 4);
                Ws[wq * 8 + 0][wn] = v0.x;
                Ws[wq * 8 + 1][wn] = v0.y;
                Ws[wq * 8 + 2][wn] = v0.z;
                Ws[wq * 8 + 3][wn] = v0.w;
                Ws[wq * 8 + 4][wn] = v1.x;
                Ws[wq * 8 + 5][wn] = v1.y;
                Ws[wq * 8 + 6][wn] = v1.z;
                Ws[wq * 8 + 7][wn] = v1.w;
            }
            __syncthreads();
#pragma unroll
            for (int k = 0; k < 16; ++k) {
                float a[4], b[8];
#pragma unroll
                for (int i = 0; i < 4; ++i) a[i] = As[ty * 4 + i][k];
#pragma unroll
                for (int j = 0; j < 8; ++j) b[j] = Ws[k][tx + 16 * j];
#pragma unroll
                for (int i = 0; i < 4; ++i)
#pragma unroll
                    for (int j = 0; j < 8; ++j) acc[i][j] += a[i] * b[j];
            }
        }
    }

    float g[8], be[8], bc[8];
#pragma unroll
    for (int j = 0; j < 8; ++j) {
        int c = tx + 16 * j;
        bc[j] = bconv[c];
        g[j] = gamma[c];
        be[j] = beta[c];
    }
#pragma unroll
    for (int i = 0; i < 4; ++i) {
        int r = row0 + ty * 4 + i;
        float s = 0.f, ss = 0.f;
#pragma unroll
        for (int j = 0; j < 8; ++j) {
            float h = acc[i][j] + bc[j];
            acc[i][j] = h;
            s += h;
            ss += h * h;
        }
#pragma unroll
        for (int m = 1; m < 16; m <<= 1) {
            s += __shfl_xor(s, m, 64);
            ss += __shfl_xor(ss, m, 64);
        }
        float mu = s * (1.0f / 128.0f);
        float var = ss * (1.0f / 128.0f) - mu * mu;
        float rs = rsqrtf(var + 1e-5f);
        if (r < n) {
#pragma unroll
            for (int j = 0; j < 8; ++j) {
                float o = (acc[i][j] - mu) * rs * g[j] + be[j];
                Xout[(size_t)r * C + tx + 16 * j] = fmaxf(o, 0.f);
            }
        }
    }
}

// ---------------- head: out = x[:ns] @ Wh^T + bh ----------------
__global__ void head_kernel(const float* __restrict__ x, const float* __restrict__ Wh,
                            const float* __restrict__ bh, float* __restrict__ out) {
    __shared__ float xs[C];
    int s = blockIdx.x;
    int o = threadIdx.x;  // 64 threads
    xs[o] = x[(size_t)s * C + o];
    xs[o + 64] = x[(size_t)s * C + o + 64];
    __syncthreads();
    float acc = bh[o];
    const float4* wr = (const float4*)(Wh + (size_t)o * C);
#pragma unroll
    for (int c4 = 0; c4 < 32; ++c4) {
        float4 w = wr[c4];
        acc += w.x * xs[c4 * 4] + w.y * xs[c4 * 4 + 1] + w.z * xs[c4 * 4 + 2] + w.w * xs[c4 * 4 + 3];
    }
    out[(size_t)s * 64 + o] = acc;
}

extern "C" void kernel_launch(void* const* d_in, const int* in_sizes, int n_in,
                              void* d_out, int out_size, void* d_ws, size_t ws_size,
                              hipStream_t stream) {
    const float* x = (const float*)d_in[0];
    const int* ei = (const int*)d_in[1];
    const float* Wn = (const float*)d_in[2];
    const float* Wr = (const float*)d_in[3];
    const float* bconv = (const float*)d_in[4];
    const float* gamma = (const float*)d_in[5];
    const float* beta = (const float*)d_in[6];
    const float* Wh = (const float*)d_in[7];
    const float* bh = (const float*)d_in[8];

    int N = in_sizes[0] / C;
    int E = in_sizes[1] / 2;
    int L = in_sizes[2] / (C * C);
    int num_seed = out_size / 64;
    int nchunks = (N + 255) / 256;

    char* ws = (char*)d_ws;
    size_t off = 0;
    auto alloc = [&](size_t bytes) {
        void* p = ws + off;
        off = (off + bytes + 255) & ~(size_t)255;
        return p;
    };
    int* deg = (int*)alloc((size_t)N * 4);
    int* row_start = (int*)alloc((size_t)(N + 1) * 4);
    int* cursor = (int*)alloc((size_t)N * 4);
    float* inv_deg = (float*)alloc((size_t)N * 4);
    int* blocksum = (int*)alloc((size_t)nchunks * 4);
    int* blockoff = (int*)alloc((size_t)nchunks * 4);
    int* esrc = (int*)alloc((size_t)E * 4);
    float* agg = (float*)alloc((size_t)N * C * 4);
    float* xA = (float*)alloc((size_t)N * C * 4);
    float* xB = (float*)alloc((size_t)N * C * 4);

    const int* srcIdx = ei;
    const int* dstIdx = ei + E;

    hipMemsetAsync(deg, 0, (size_t)N * 4, stream);
    count_deg_kernel<<<(E + 255) / 256, 256, 0, stream>>>(dstIdx, deg, E);
    scan_partial_kernel<<<nchunks, 256, 0, stream>>>(deg, blocksum, N);
    scan_block_kernel<<<1, 256, 0, stream>>>(blocksum, blockoff, nchunks);
    scan_scatter_kernel<<<nchunks, 256, 0, stream>>>(deg, blockoff, row_start, cursor, inv_deg, N, E);
    bucket_kernel<<<(E + 255) / 256, 256, 0, stream>>>(srcIdx, dstIdx, cursor, esrc, E);

    const float* cur = x;
    float* bufs[2] = {xA, xB};
    for (int l = 0; l < L; ++l) {
        aggregate_kernel<<<(N * 64 + 255) / 256, 256, 0, stream>>>(cur, row_start, esrc, inv_deg, agg, N);
        float* nxt = bufs[l & 1];
        gemm_ln_relu_kernel<<<(N + 63) / 64, 256, 0, stream>>>(
            agg, cur, Wn + (size_t)l * C * C, Wr + (size_t)l * C * C,
            bconv + (size_t)l * C, gamma + (size_t)l * C, beta + (size_t)l * C, nxt, N);
        cur = nxt;
    }
    head_kernel<<<num_seed, 64, 0, stream>>>(cur, Wh, bh, (float*)d_out);
}

// Round 3
// 297.564 us; speedup vs baseline: 1.7914x; 1.3320x over previous
//
#include <hip/hip_runtime.h>

#define C 128

typedef __attribute__((ext_vector_type(8))) short short8;
typedef __attribute__((ext_vector_type(16))) float floatx16;

__device__ __forceinline__ unsigned short f2b(float f) {
    union { float f; unsigned u; } v; v.f = f;
    unsigned u = v.u + 0x7fffu + ((v.u >> 16) & 1u);  // RNE
    return (unsigned short)(u >> 16);
}
__device__ __forceinline__ float b2f(unsigned short h) {
    union { unsigned u; float f; } v; v.u = ((unsigned)h) << 16;
    return v.f;
}

// ---------------- fp32 -> bf16 cast (x and weights, once) ----------------
__global__ void cast_f32_bf16_kernel(const float* __restrict__ in, unsigned short* __restrict__ out, int n4) {
    int i = blockIdx.x * blockDim.x + threadIdx.x;
    if (i < n4) {
        float4 v = ((const float4*)in)[i];
        ushort4 o;
        o.x = f2b(v.x); o.y = f2b(v.y); o.z = f2b(v.z); o.w = f2b(v.w);
        ((ushort4*)out)[i] = o;
    }
}

// ---------------- degree histogram ----------------
__global__ void count_deg_kernel(const int* __restrict__ dst, int* __restrict__ deg, int E) {
    int e = blockIdx.x * blockDim.x + threadIdx.x;
    if (e < E) atomicAdd(&deg[dst[e]], 1);
}

// ---------------- parallel exclusive scan over deg[] (3 phases) ----------------
__global__ void scan_partial_kernel(const int* __restrict__ deg, int* __restrict__ blocksum, int n) {
    __shared__ int sm[256];
    int t = threadIdx.x;
    int i = blockIdx.x * 256 + t;
    sm[t] = (i < n) ? deg[i] : 0;
    __syncthreads();
#pragma unroll
    for (int off = 128; off > 0; off >>= 1) {
        if (t < off) sm[t] += sm[t + off];
        __syncthreads();
    }
    if (t == 0) blocksum[blockIdx.x] = sm[0];
}

__global__ void scan_block_kernel(const int* __restrict__ blocksum, int* __restrict__ blockoff, int nb) {
    __shared__ int sm[256];
    int t = threadIdx.x;
    int chunk = (nb + 255) / 256;
    int begin = t * chunk, end = min(begin + chunk, nb);
    int s = 0;
    for (int i = begin; i < end; ++i) s += blocksum[i];
    sm[t] = s;
    __syncthreads();
    for (int off = 1; off < 256; off <<= 1) {
        int v = (t >= off) ? sm[t - off] : 0;
        __syncthreads();
        sm[t] += v;
        __syncthreads();
    }
    int run = (t == 0) ? 0 : sm[t - 1];
    for (int i = begin; i < end; ++i) {
        blockoff[i] = run;
        run += blocksum[i];
    }
}

__global__ void scan_scatter_kernel(const int* __restrict__ deg, const int* __restrict__ blockoff,
                                    int* __restrict__ row_start, int* __restrict__ cursor,
                                    float* __restrict__ inv_deg, int n, int E) {
    __shared__ int sm[256];
    int t = threadIdx.x;
    int i = blockIdx.x * 256 + t;
    int d = (i < n) ? deg[i] : 0;
    sm[t] = d;
    __syncthreads();
    for (int off = 1; off < 256; off <<= 1) {
        int v = (t >= off) ? sm[t - off] : 0;
        __syncthreads();
        sm[t] += v;
        __syncthreads();
    }
    int excl = sm[t] - d + blockoff[blockIdx.x];
    if (i < n) {
        row_start[i] = excl;
        cursor[i] = excl;
        inv_deg[i] = 1.0f / fmaxf((float)d, 1.0f);
    }
    if (i == n - 1) row_start[n] = E;
}

// ---------------- bucket edges by dst (counting sort) ----------------
__global__ void bucket_kernel(const int* __restrict__ src, const int* __restrict__ dst,
                              int* __restrict__ cursor, int* __restrict__ esrc, int E) {
    int e = blockIdx.x * blockDim.x + threadIdx.x;
    if (e < E) {
        int d = dst[e];
        int p = atomicAdd(&cursor[d], 1);
        esrc[p] = src[e];
    }
}

// ---------------- mean aggregation (bf16 in/out, fp32 accumulate) ----------------
__global__ void aggregate_kernel(const unsigned short* __restrict__ xb, const int* __restrict__ row_start,
                                 const int* __restrict__ esrc, const float* __restrict__ inv_deg,
                                 unsigned short* __restrict__ agg, int n) {
    int wave = (blockIdx.x * blockDim.x + threadIdx.x) >> 6;
    int lane = threadIdx.x & 63;
    if (wave >= n) return;
    int beg = row_start[wave];
    int end = row_start[wave + 1];
    float ax = 0.f, ay = 0.f;
    int i = beg;
    for (; i + 1 < end; i += 2) {
        int s0 = esrc[i], s1 = esrc[i + 1];
        unsigned u0 = *(const unsigned*)(xb + (size_t)s0 * C + lane * 2);
        unsigned u1 = *(const unsigned*)(xb + (size_t)s1 * C + lane * 2);
        ax += b2f((unsigned short)u0) + b2f((unsigned short)u1);
        ay += b2f((unsigned short)(u0 >> 16)) + b2f((unsigned short)(u1 >> 16));
    }
    if (i < end) {
        unsigned u0 = *(const unsigned*)(xb + (size_t)esrc[i] * C + lane * 2);
        ax += b2f((unsigned short)u0);
        ay += b2f((unsigned short)(u0 >> 16));
    }
    float sc = inv_deg[wave];
    unsigned o = ((unsigned)f2b(ay * sc) << 16) | (unsigned)f2b(ax * sc);
    *(unsigned*)(agg + (size_t)wave * C + lane * 2) = o;
}

// ---------------- MFMA GEMM (h = agg@Wn^T + x@Wr^T + b) + LayerNorm + ReLU ----------------
// Block: 64 rows x 128 cols, 4 waves. Wave w: rows [(w&1)*32, +32), cols [(w>>1)*64, +64)
// via two v_mfma_f32_32x32x16_bf16 accumulators. K = 128 per phase, 2 phases (Wn/agg, Wr/x).
// LDS stride 136 shorts (272 B = 68 words): row r start bank = 4r%32 -> every bank gets
// exactly 8 accesses per wave ds_read_b128 = conflict-free minimum.
__launch_bounds__(256)
__global__ void gemm_mfma_ln_relu_kernel(const unsigned short* __restrict__ Aagg,
                                         const unsigned short* __restrict__ Xin,
                                         const unsigned short* __restrict__ Wn,
                                         const unsigned short* __restrict__ Wr,
                                         const float* __restrict__ bconv, const float* __restrict__ gamma,
                                         const float* __restrict__ beta, unsigned short* __restrict__ Xout,
                                         int n) {
    __shared__ unsigned short Xs[64][136];
    __shared__ unsigned short Ws[128][136];
    __shared__ float Ls[64][2];
    __shared__ float Lss[64][2];

    int tid = threadIdx.x;
    int wave = tid >> 6, lane = tid & 63;
    int rh = wave & 1, ch = wave >> 1;
    int l31 = lane & 31, half = lane >> 5;
    int row0 = blockIdx.x * 64;

    floatx16 acc0, acc1;
#pragma unroll
    for (int i = 0; i < 16; ++i) { acc0[i] = 0.f; acc1[i] = 0.f; }

    for (int phase = 0; phase < 2; ++phase) {
        const unsigned short* Ap = phase ? Xin : Aagg;
        const unsigned short* Wp = phase ? Wr : Wn;
        __syncthreads();
        // stage A tile: 64 rows x 128 bf16 = 1024 16B-chunks, 4 per thread (coalesced)
#pragma unroll
        for (int i = 0; i < 4; ++i) {
            int cidx = tid + 256 * i;
            int r = cidx >> 4, koff = (cidx & 15) * 8;
            uint4 v = make_uint4(0u, 0u, 0u, 0u);
            int rg = row0 + r;
            if (rg < n) v = *(const uint4*)(Ap + (size_t)rg * C + koff);
            *(uint4*)&Xs[r][koff] = v;
        }
        // stage W: 128 rows x 128 bf16 = 2048 chunks, 8 per thread
#pragma unroll
        for (int i = 0; i < 8; ++i) {
            int cidx = tid + 256 * i;
            int r = cidx >> 4, koff = (cidx & 15) * 8;
            uint4 v = *(const uint4*)(Wp + (size_t)r * C + koff);
            *(uint4*)&Ws[r][koff] = v;
        }
        __syncthreads();
#pragma unroll
        for (int kc = 0; kc < C; kc += 16) {
            int ko = kc + half * 8;
            short8 a = *(const short8*)&Xs[rh * 32 + l31][ko];
            short8 b0 = *(const short8*)&Ws[ch * 64 + l31][ko];
            short8 b1 = *(const short8*)&Ws[ch * 64 + 32 + l31][ko];
            acc0 = __builtin_amdgcn_mfma_f32_32x32x16_bf16(a, b0, acc0, 0, 0, 0);
            acc1 = __builtin_amdgcn_mfma_f32_32x32x16_bf16(a, b1, acc1, 0, 0, 0);
        }
    }

    // epilogue: bias, LayerNorm across 128 cols (spread over 2 waves), ReLU, bf16 store
    int col0 = ch * 64 + l31;
    int col1 = col0 + 32;
    float bc0 = bconv[col0], bc1 = bconv[col1];
#pragma unroll
    for (int r = 0; r < 16; ++r) {
        float h0 = acc0[r] + bc0;
        float h1 = acc1[r] + bc1;
        float s = h0 + h1, ss = h0 * h0 + h1 * h1;
#pragma unroll
        for (int m = 1; m < 32; m <<= 1) {
            s += __shfl_xor(s, m, 64);
            ss += __shfl_xor(ss, m, 64);
        }
        if (l31 == 0) {
            int row_l = rh * 32 + (r & 3) + 8 * (r >> 2) + 4 * half;
            Ls[row_l][ch] = s;
            Lss[row_l][ch] = ss;
        }
    }
    __syncthreads();
    float g0 = gamma[col0], g1 = gamma[col1];
    float be0 = beta[col0], be1 = beta[col1];
#pragma unroll
    for (int r = 0; r < 16; ++r) {
        int row_l = rh * 32 + (r & 3) + 8 * (r >> 2) + 4 * half;
        int rg = row0 + row_l;
        if (rg < n) {
            float s = Ls[row_l][0] + Ls[row_l][1];
            float ss = Lss[row_l][0] + Lss[row_l][1];
            float mu = s * (1.0f / 128.0f);
            float var = ss * (1.0f / 128.0f) - mu * mu;
            float rs = rsqrtf(var + 1e-5f);
            float h0 = acc0[r] + bc0;
            float h1 = acc1[r] + bc1;
            float o0 = fmaxf((h0 - mu) * rs * g0 + be0, 0.f);
            float o1 = fmaxf((h1 - mu) * rs * g1 + be1, 0.f);
            Xout[(size_t)rg * C + col0] = f2b(o0);
            Xout[(size_t)rg * C + col1] = f2b(o1);
        }
    }
}

// ---------------- head: out = x[:ns] @ Wh^T + bh (bf16 x, fp32 W/out) ----------------
__global__ void head_kernel(const unsigned short* __restrict__ xb, const float* __restrict__ Wh,
                            const float* __restrict__ bh, float* __restrict__ out) {
    __shared__ float xs[C];
    int s = blockIdx.x;
    int o = threadIdx.x;  // 64 threads
    xs[o] = b2f(xb[(size_t)s * C + o]);
    xs[o + 64] = b2f(xb[(size_t)s * C + o + 64]);
    __syncthreads();
    float acc = bh[o];
    const float4* wr = (const float4*)(Wh + (size_t)o * C);
#pragma unroll
    for (int c4 = 0; c4 < 32; ++c4) {
        float4 w = wr[c4];
        acc += w.x * xs[c4 * 4] + w.y * xs[c4 * 4 + 1] + w.z * xs[c4 * 4 + 2] + w.w * xs[c4 * 4 + 3];
    }
    out[(size_t)s * 64 + o] = acc;
}

extern "C" void kernel_launch(void* const* d_in, const int* in_sizes, int n_in,
                              void* d_out, int out_size, void* d_ws, size_t ws_size,
                              hipStream_t stream) {
    const float* x = (const float*)d_in[0];
    const int* ei = (const int*)d_in[1];
    const float* Wn = (const float*)d_in[2];
    const float* Wr = (const float*)d_in[3];
    const float* bconv = (const float*)d_in[4];
    const float* gamma = (const float*)d_in[5];
    const float* beta = (const float*)d_in[6];
    const float* Wh = (const float*)d_in[7];
    const float* bh = (const float*)d_in[8];

    int N = in_sizes[0] / C;
    int E = in_sizes[1] / 2;
    int L = in_sizes[2] / (C * C);
    int num_seed = out_size / 64;
    int nchunks = (N + 255) / 256;

    char* ws = (char*)d_ws;
    size_t off = 0;
    auto alloc = [&](size_t bytes) {
        void* p = ws + off;
        off = (off + bytes + 255) & ~(size_t)255;
        return p;
    };
    int* deg = (int*)alloc((size_t)N * 4);
    int* row_start = (int*)alloc((size_t)(N + 1) * 4);
    int* cursor = (int*)alloc((size_t)N * 4);
    float* inv_deg = (float*)alloc((size_t)N * 4);
    int* blocksum = (int*)alloc((size_t)nchunks * 4);
    int* blockoff = (int*)alloc((size_t)nchunks * 4);
    int* esrc = (int*)alloc((size_t)E * 4);
    unsigned short* xb = (unsigned short*)alloc((size_t)N * C * 2);
    unsigned short* aggb = (unsigned short*)alloc((size_t)N * C * 2);
    unsigned short* xA = (unsigned short*)alloc((size_t)N * C * 2);
    unsigned short* xB = (unsigned short*)alloc((size_t)N * C * 2);
    unsigned short* Wnb = (unsigned short*)alloc((size_t)L * C * C * 2);
    unsigned short* Wrb = (unsigned short*)alloc((size_t)L * C * C * 2);

    const int* srcIdx = ei;
    const int* dstIdx = ei + E;

    // casts
    int n4x = N * C / 4;
    cast_f32_bf16_kernel<<<(n4x + 255) / 256, 256, 0, stream>>>(x, xb, n4x);
    int n4w = L * C * C / 4;
    cast_f32_bf16_kernel<<<(n4w + 255) / 256, 256, 0, stream>>>(Wn, Wnb, n4w);
    cast_f32_bf16_kernel<<<(n4w + 255) / 256, 256, 0, stream>>>(Wr, Wrb, n4w);

    // CSR build
    hipMemsetAsync(deg, 0, (size_t)N * 4, stream);
    count_deg_kernel<<<(E + 255) / 256, 256, 0, stream>>>(dstIdx, deg, E);
    scan_partial_kernel<<<nchunks, 256, 0, stream>>>(deg, blocksum, N);
    scan_block_kernel<<<1, 256, 0, stream>>>(blocksum, blockoff, nchunks);
    scan_scatter_kernel<<<nchunks, 256, 0, stream>>>(deg, blockoff, row_start, cursor, inv_deg, N, E);
    bucket_kernel<<<(E + 255) / 256, 256, 0, stream>>>(srcIdx, dstIdx, cursor, esrc, E);

    const unsigned short* cur = xb;
    unsigned short* bufs[2] = {xA, xB};
    for (int l = 0; l < L; ++l) {
        aggregate_kernel<<<(N * 64 + 255) / 256, 256, 0, stream>>>(cur, row_start, esrc, inv_deg, aggb, N);
        unsigned short* nxt = bufs[l & 1];
        gemm_mfma_ln_relu_kernel<<<(N + 63) / 64, 256, 0, stream>>>(
            aggb, cur, Wnb + (size_t)l * C * C, Wrb + (size_t)l * C * C,
            bconv + (size_t)l * C, gamma + (size_t)l * C, beta + (size_t)l * C, nxt, N);
        cur = nxt;
    }
    head_kernel<<<num_seed, 64, 0, stream>>>(cur, Wh, bh, (float*)d_out);
}

// Round 4
// 267.633 us; speedup vs baseline: 1.9918x; 1.1118x over previous
//
#include <hip/hip_runtime.h>

#define C 128

typedef __attribute__((ext_vector_type(8))) short short8;
typedef __attribute__((ext_vector_type(16))) float floatx16;

__device__ __forceinline__ unsigned short f2b(float f) {
    union { float f; unsigned u; } v; v.f = f;
    unsigned u = v.u + 0x7fffu + ((v.u >> 16) & 1u);  // RNE
    return (unsigned short)(u >> 16);
}
__device__ __forceinline__ float b2f(unsigned short h) {
    union { unsigned u; float f; } v; v.u = ((unsigned)h) << 16;
    return v.f;
}
// accumulate the two bf16 packed in u into lo/hi fp32 accumulators
__device__ __forceinline__ void acc_pair(unsigned u, float& lo, float& hi) {
    union { unsigned u; float f; } a, b;
    a.u = u << 16;
    b.u = u & 0xffff0000u;
    lo += a.f;
    hi += b.f;
}

// ---------------- fp32 -> bf16 cast (x and weights, once) ----------------
__global__ void cast_f32_bf16_kernel(const float* __restrict__ in, unsigned short* __restrict__ out, int n4) {
    int i = blockIdx.x * blockDim.x + threadIdx.x;
    if (i < n4) {
        float4 v = ((const float4*)in)[i];
        ushort4 o;
        o.x = f2b(v.x); o.y = f2b(v.y); o.z = f2b(v.z); o.w = f2b(v.w);
        ((ushort4*)out)[i] = o;
    }
}

// ---------------- degree histogram ----------------
__global__ void count_deg_kernel(const int* __restrict__ dst, int* __restrict__ deg, int E) {
    int e = blockIdx.x * blockDim.x + threadIdx.x;
    if (e < E) atomicAdd(&deg[dst[e]], 1);
}

// ---------------- parallel exclusive scan over deg[] (3 phases) ----------------
__global__ void scan_partial_kernel(const int* __restrict__ deg, int* __restrict__ blocksum, int n) {
    __shared__ int sm[256];
    int t = threadIdx.x;
    int i = blockIdx.x * 256 + t;
    sm[t] = (i < n) ? deg[i] : 0;
    __syncthreads();
#pragma unroll
    for (int off = 128; off > 0; off >>= 1) {
        if (t < off) sm[t] += sm[t + off];
        __syncthreads();
    }
    if (t == 0) blocksum[blockIdx.x] = sm[0];
}

__global__ void scan_block_kernel(const int* __restrict__ blocksum, int* __restrict__ blockoff, int nb) {
    __shared__ int sm[256];
    int t = threadIdx.x;
    int chunk = (nb + 255) / 256;
    int begin = t * chunk, end = min(begin + chunk, nb);
    int s = 0;
    for (int i = begin; i < end; ++i) s += blocksum[i];
    sm[t] = s;
    __syncthreads();
    for (int off = 1; off < 256; off <<= 1) {
        int v = (t >= off) ? sm[t - off] : 0;
        __syncthreads();
        sm[t] += v;
        __syncthreads();
    }
    int run = (t == 0) ? 0 : sm[t - 1];
    for (int i = begin; i < end; ++i) {
        blockoff[i] = run;
        run += blocksum[i];
    }
}

__global__ void scan_scatter_kernel(const int* __restrict__ deg, const int* __restrict__ blockoff,
                                    int* __restrict__ row_start, int* __restrict__ cursor,
                                    float* __restrict__ inv_deg, int n, int E) {
    __shared__ int sm[256];
    int t = threadIdx.x;
    int i = blockIdx.x * 256 + t;
    int d = (i < n) ? deg[i] : 0;
    sm[t] = d;
    __syncthreads();
    for (int off = 1; off < 256; off <<= 1) {
        int v = (t >= off) ? sm[t - off] : 0;
        __syncthreads();
        sm[t] += v;
        __syncthreads();
    }
    int excl = sm[t] - d + blockoff[blockIdx.x];
    if (i < n) {
        row_start[i] = excl;
        cursor[i] = excl;
        inv_deg[i] = 1.0f / fmaxf((float)d, 1.0f);
    }
    if (i == n - 1) row_start[n] = E;
}

// ---------------- bucket edges by dst (counting sort) ----------------
__global__ void bucket_kernel(const int* __restrict__ src, const int* __restrict__ dst,
                              int* __restrict__ cursor, int* __restrict__ esrc, int E) {
    int e = blockIdx.x * blockDim.x + threadIdx.x;
    if (e < E) {
        int d = dst[e];
        int p = atomicAdd(&cursor[d], 1);
        esrc[p] = src[e];
    }
}

// ---------------- mean aggregation (bf16, uint4 gathers, 4 edges/wave-iter) ----------------
// One wave per node. Quarter q = lane>>4 handles edges beg+q, beg+q+4, ...
// Each of the 16 lanes in a quarter loads uint4 = 8 bf16 channels -> 4 edge-rows
// per wave load instruction, unrolled x2 -> 8 x 256B outstanding per wave.
__global__ void aggregate_kernel(const unsigned short* __restrict__ xb, const int* __restrict__ row_start,
                                 const int* __restrict__ esrc, const float* __restrict__ inv_deg,
                                 unsigned short* __restrict__ agg, int n) {
    int wid = (blockIdx.x * blockDim.x + threadIdx.x) >> 6;
    int lane = threadIdx.x & 63;
    if (wid >= n) return;
    int beg = row_start[wid];
    int end = row_start[wid + 1];
    int q = lane >> 4;
    int l16 = lane & 15;
    size_t choff = (size_t)l16 * 8;

    float a0 = 0.f, a1 = 0.f, a2 = 0.f, a3 = 0.f, a4 = 0.f, a5 = 0.f, a6 = 0.f, a7 = 0.f;

    int i = beg + q;
    for (; i + 4 < end; i += 8) {
        int s0 = esrc[i], s1 = esrc[i + 4];
        uint4 v0 = *(const uint4*)(xb + (size_t)s0 * C + choff);
        uint4 v1 = *(const uint4*)(xb + (size_t)s1 * C + choff);
        acc_pair(v0.x, a0, a1); acc_pair(v0.y, a2, a3);
        acc_pair(v0.z, a4, a5); acc_pair(v0.w, a6, a7);
        acc_pair(v1.x, a0, a1); acc_pair(v1.y, a2, a3);
        acc_pair(v1.z, a4, a5); acc_pair(v1.w, a6, a7);
    }
    if (i < end) {
        uint4 v0 = *(const uint4*)(xb + (size_t)esrc[i] * C + choff);
        acc_pair(v0.x, a0, a1); acc_pair(v0.y, a2, a3);
        acc_pair(v0.z, a4, a5); acc_pair(v0.w, a6, a7);
    }

    // fold the 4 quarter-partials (channels align across quarters)
#pragma unroll
    for (int m = 16; m <= 32; m <<= 1) {
        a0 += __shfl_xor(a0, m, 64); a1 += __shfl_xor(a1, m, 64);
        a2 += __shfl_xor(a2, m, 64); a3 += __shfl_xor(a3, m, 64);
        a4 += __shfl_xor(a4, m, 64); a5 += __shfl_xor(a5, m, 64);
        a6 += __shfl_xor(a6, m, 64); a7 += __shfl_xor(a7, m, 64);
    }

    if (q == 0) {
        float sc = inv_deg[wid];
        uint4 o;
        o.x = ((unsigned)f2b(a1 * sc) << 16) | (unsigned)f2b(a0 * sc);
        o.y = ((unsigned)f2b(a3 * sc) << 16) | (unsigned)f2b(a2 * sc);
        o.z = ((unsigned)f2b(a5 * sc) << 16) | (unsigned)f2b(a4 * sc);
        o.w = ((unsigned)f2b(a7 * sc) << 16) | (unsigned)f2b(a6 * sc);
        *(uint4*)(agg + (size_t)wid * C + choff) = o;
    }
}

// ---------------- MFMA GEMM (h = agg@Wn^T + x@Wr^T + b) + LayerNorm + ReLU ----------------
__launch_bounds__(256)
__global__ void gemm_mfma_ln_relu_kernel(const unsigned short* __restrict__ Aagg,
                                         const unsigned short* __restrict__ Xin,
                                         const unsigned short* __restrict__ Wn,
                                         const unsigned short* __restrict__ Wr,
                                         const float* __restrict__ bconv, const float* __restrict__ gamma,
                                         const float* __restrict__ beta, unsigned short* __restrict__ Xout,
                                         int n) {
    __shared__ unsigned short Xs[64][136];
    __shared__ unsigned short Ws[128][136];
    __shared__ float Ls[64][2];
    __shared__ float Lss[64][2];

    int tid = threadIdx.x;
    int wave = tid >> 6, lane = tid & 63;
    int rh = wave & 1, ch = wave >> 1;
    int l31 = lane & 31, half = lane >> 5;
    int row0 = blockIdx.x * 64;

    floatx16 acc0, acc1;
#pragma unroll
    for (int i = 0; i < 16; ++i) { acc0[i] = 0.f; acc1[i] = 0.f; }

    for (int phase = 0; phase < 2; ++phase) {
        const unsigned short* Ap = phase ? Xin : Aagg;
        const unsigned short* Wp = phase ? Wr : Wn;
        __syncthreads();
#pragma unroll
        for (int i = 0; i < 4; ++i) {
            int cidx = tid + 256 * i;
            int r = cidx >> 4, koff = (cidx & 15) * 8;
            uint4 v = make_uint4(0u, 0u, 0u, 0u);
            int rg = row0 + r;
            if (rg < n) v = *(const uint4*)(Ap + (size_t)rg * C + koff);
            *(uint4*)&Xs[r][koff] = v;
        }
#pragma unroll
        for (int i = 0; i < 8; ++i) {
            int cidx = tid + 256 * i;
            int r = cidx >> 4, koff = (cidx & 15) * 8;
            uint4 v = *(const uint4*)(Wp + (size_t)r * C + koff);
            *(uint4*)&Ws[r][koff] = v;
        }
        __syncthreads();
#pragma unroll
        for (int kc = 0; kc < C; kc += 16) {
            int ko = kc + half * 8;
            short8 a = *(const short8*)&Xs[rh * 32 + l31][ko];
            short8 b0 = *(const short8*)&Ws[ch * 64 + l31][ko];
            short8 b1 = *(const short8*)&Ws[ch * 64 + 32 + l31][ko];
            acc0 = __builtin_amdgcn_mfma_f32_32x32x16_bf16(a, b0, acc0, 0, 0, 0);
            acc1 = __builtin_amdgcn_mfma_f32_32x32x16_bf16(a, b1, acc1, 0, 0, 0);
        }
    }

    int col0 = ch * 64 + l31;
    int col1 = col0 + 32;
    float bc0 = bconv[col0], bc1 = bconv[col1];
#pragma unroll
    for (int r = 0; r < 16; ++r) {
        float h0 = acc0[r] + bc0;
        float h1 = acc1[r] + bc1;
        float s = h0 + h1, ss = h0 * h0 + h1 * h1;
#pragma unroll
        for (int m = 1; m < 32; m <<= 1) {
            s += __shfl_xor(s, m, 64);
            ss += __shfl_xor(ss, m, 64);
        }
        if (l31 == 0) {
            int row_l = rh * 32 + (r & 3) + 8 * (r >> 2) + 4 * half;
            Ls[row_l][ch] = s;
            Lss[row_l][ch] = ss;
        }
    }
    __syncthreads();
    float g0 = gamma[col0], g1 = gamma[col1];
    float be0 = beta[col0], be1 = beta[col1];
#pragma unroll
    for (int r = 0; r < 16; ++r) {
        int row_l = rh * 32 + (r & 3) + 8 * (r >> 2) + 4 * half;
        int rg = row0 + row_l;
        if (rg < n) {
            float s = Ls[row_l][0] + Ls[row_l][1];
            float ss = Lss[row_l][0] + Lss[row_l][1];
            float mu = s * (1.0f / 128.0f);
            float var = ss * (1.0f / 128.0f) - mu * mu;
            float rs = rsqrtf(var + 1e-5f);
            float h0 = acc0[r] + bc0;
            float h1 = acc1[r] + bc1;
            float o0 = fmaxf((h0 - mu) * rs * g0 + be0, 0.f);
            float o1 = fmaxf((h1 - mu) * rs * g1 + be1, 0.f);
            Xout[(size_t)rg * C + col0] = f2b(o0);
            Xout[(size_t)rg * C + col1] = f2b(o1);
        }
    }
}

// ---------------- head: out = x[:ns] @ Wh^T + bh (bf16 x, fp32 W/out) ----------------
__global__ void head_kernel(const unsigned short* __restrict__ xb, const float* __restrict__ Wh,
                            const float* __restrict__ bh, float* __restrict__ out) {
    __shared__ float xs[C];
    int s = blockIdx.x;
    int o = threadIdx.x;  // 64 threads
    xs[o] = b2f(xb[(size_t)s * C + o]);
    xs[o + 64] = b2f(xb[(size_t)s * C + o + 64]);
    __syncthreads();
    float acc = bh[o];
    const float4* wr = (const float4*)(Wh + (size_t)o * C);
#pragma unroll
    for (int c4 = 0; c4 < 32; ++c4) {
        float4 w = wr[c4];
        acc += w.x * xs[c4 * 4] + w.y * xs[c4 * 4 + 1] + w.z * xs[c4 * 4 + 2] + w.w * xs[c4 * 4 + 3];
    }
    out[(size_t)s * 64 + o] = acc;
}

extern "C" void kernel_launch(void* const* d_in, const int* in_sizes, int n_in,
                              void* d_out, int out_size, void* d_ws, size_t ws_size,
                              hipStream_t stream) {
    const float* x = (const float*)d_in[0];
    const int* ei = (const int*)d_in[1];
    const float* Wn = (const float*)d_in[2];
    const float* Wr = (const float*)d_in[3];
    const float* bconv = (const float*)d_in[4];
    const float* gamma = (const float*)d_in[5];
    const float* beta = (const float*)d_in[6];
    const float* Wh = (const float*)d_in[7];
    const float* bh = (const float*)d_in[8];

    int N = in_sizes[0] / C;
    int E = in_sizes[1] / 2;
    int L = in_sizes[2] / (C * C);
    int num_seed = out_size / 64;
    int nchunks = (N + 255) / 256;

    char* ws = (char*)d_ws;
    size_t off = 0;
    auto alloc = [&](size_t bytes) {
        void* p = ws + off;
        off = (off + bytes + 255) & ~(size_t)255;
        return p;
    };
    int* deg = (int*)alloc((size_t)N * 4);
    int* row_start = (int*)alloc((size_t)(N + 1) * 4);
    int* cursor = (int*)alloc((size_t)N * 4);
    float* inv_deg = (float*)alloc((size_t)N * 4);
    int* blocksum = (int*)alloc((size_t)nchunks * 4);
    int* blockoff = (int*)alloc((size_t)nchunks * 4);
    int* esrc = (int*)alloc((size_t)E * 4);
    unsigned short* xb = (unsigned short*)alloc((size_t)N * C * 2);
    unsigned short* aggb = (unsigned short*)alloc((size_t)N * C * 2);
    unsigned short* xA = (unsigned short*)alloc((size_t)N * C * 2);
    unsigned short* xB = (unsigned short*)alloc((size_t)N * C * 2);
    unsigned short* Wnb = (unsigned short*)alloc((size_t)L * C * C * 2);
    unsigned short* Wrb = (unsigned short*)alloc((size_t)L * C * C * 2);

    const int* srcIdx = ei;
    const int* dstIdx = ei + E;

    int n4x = N * C / 4;
    cast_f32_bf16_kernel<<<(n4x + 255) / 256, 256, 0, stream>>>(x, xb, n4x);
    int n4w = L * C * C / 4;
    cast_f32_bf16_kernel<<<(n4w + 255) / 256, 256, 0, stream>>>(Wn, Wnb, n4w);
    cast_f32_bf16_kernel<<<(n4w + 255) / 256, 256, 0, stream>>>(Wr, Wrb, n4w);

    hipMemsetAsync(deg, 0, (size_t)N * 4, stream);
    count_deg_kernel<<<(E + 255) / 256, 256, 0, stream>>>(dstIdx, deg, E);
    scan_partial_kernel<<<nchunks, 256, 0, stream>>>(deg, blocksum, N);
    scan_block_kernel<<<1, 256, 0, stream>>>(blocksum, blockoff, nchunks);
    scan_scatter_kernel<<<nchunks, 256, 0, stream>>>(deg, blockoff, row_start, cursor, inv_deg, N, E);
    bucket_kernel<<<(E + 255) / 256, 256, 0, stream>>>(srcIdx, dstIdx, cursor, esrc, E);

    const unsigned short* cur = xb;
    unsigned short* bufs[2] = {xA, xB};
    for (int l = 0; l < L; ++l) {
        aggregate_kernel<<<(N * 64 + 255) / 256, 256, 0, stream>>>(cur, row_start, esrc, inv_deg, aggb, N);
        unsigned short* nxt = bufs[l & 1];
        gemm_mfma_ln_relu_kernel<<<(N + 63) / 64, 256, 0, stream>>>(
            aggb, cur, Wnb + (size_t)l * C * C, Wrb + (size_t)l * C * C,
            bconv + (size_t)l * C, gamma + (size_t)l * C, beta + (size_t)l * C, nxt, N);
        cur = nxt;
    }
    head_kernel<<<num_seed, 64, 0, stream>>>(cur, Wh, bh, (float*)d_out);
}